// Round 10
// baseline (461.767 us; speedup 1.0000x reference)
//
#include <hip/hip_runtime.h>
#include <hip/hip_cooperative_groups.h>
#include <math.h>

namespace cg = cooperative_groups;

namespace {

constexpr int kB   = 64;
constexpr int kCin = 8;
constexpr int kR   = 800;
constexpr int kNC  = 128;
constexpr int kO   = 16;
constexpr int CT   = 256;   // fallback conversion kernel TPB
constexpr int MT   = 512;   // main/fused TPB
constexpr int NITER = 3;
constexpr size_t WS_NEEDED =
    (size_t)kNC * kO * kR * kCin * sizeof(unsigned short);  // 26,214,400 B

typedef _Float16 half2v __attribute__((ext_vector_type(2)));

__device__ __forceinline__ half2v u2h(unsigned int u) {
  union { unsigned int u; half2v h; } x;
  x.u = u;
  return x.h;
}

__device__ __forceinline__ unsigned short f2h(float f) {
  union { _Float16 h; unsigned short s; } x;
  x.h = (_Float16)f;
  return x.s;
}

// DPP quad-perm adds: xor1 = perm{1,0,3,2} = 0xB1, xor2 = perm{2,3,0,1} = 0x4E.
__device__ __forceinline__ float dpp_xor1_add(float v) {
  const int o = __builtin_amdgcn_mov_dpp(__float_as_int(v), 0xB1, 0xF, 0xF, true);
  return v + __int_as_float(o);
}
__device__ __forceinline__ float dpp_xor2_add(float v) {
  const int o = __builtin_amdgcn_mov_dpp(__float_as_int(v), 0x4E, 0xF, 0xF, true);
  return v + __int_as_float(o);
}

// ---- one (c,b) routing item: R7-proven structure (nb=1, 52 VGPR) ----------
// Stage-1 tree reads use stride-8 row ownership (rr*8+q) so the LDS bank
// index depends on q -> ~2-way instead of 4-way conflicts (R7 layout had
// bank = f(rr,col) only).
__device__ __forceinline__ void route_item(
    const float* __restrict__ x, const unsigned short* __restrict__ Wb,
    float* __restrict__ out, const int c, const int b, const int t,
    float* red, float* red2, float* shs) {
  constexpr int RST = 20;               // 17 cols + 3 pad (16B-aligned rows)
  const float* xb  = x + (size_t)b * kCin * kR;
  const bool  has2 = (t < kR - MT);     // t < 288 owns second row r2
  const int   r1   = t, r2 = MT + t;

  float P1[kO], P2[kO];
  #pragma unroll
  for (int o = 0; o < kO; ++o) P2[o] = 0.f;

  const uint4* Wc = reinterpret_cast<const uint4*>(Wb) + (size_t)c * kO * kR;
  {
    half2v xp[4];
    #pragma unroll
    for (int q = 0; q < 4; ++q)
      xp[q] = half2v{(_Float16)xb[(2*q) * kR + r1], (_Float16)xb[(2*q+1) * kR + r1]};
    #pragma unroll
    for (int o = 0; o < kO; ++o) {
      const uint4 w = Wc[(size_t)o * kR + r1];   // 16B coalesced, L2-hit
      float a = __builtin_amdgcn_fdot2(u2h(w.x), xp[0], 0.f, false);
      a = __builtin_amdgcn_fdot2(u2h(w.y), xp[1], a, false);
      a = __builtin_amdgcn_fdot2(u2h(w.z), xp[2], a, false);
      a = __builtin_amdgcn_fdot2(u2h(w.w), xp[3], a, false);
      P1[o] = a;
    }
  }
  if (has2) {
    half2v xp[4];
    #pragma unroll
    for (int q = 0; q < 4; ++q)
      xp[q] = half2v{(_Float16)xb[(2*q) * kR + r2], (_Float16)xb[(2*q+1) * kR + r2]};
    #pragma unroll
    for (int o = 0; o < kO; ++o) {
      const uint4 w = Wc[(size_t)o * kR + r2];
      float a = __builtin_amdgcn_fdot2(u2h(w.x), xp[0], 0.f, false);
      a = __builtin_amdgcn_fdot2(u2h(w.y), xp[1], a, false);
      a = __builtin_amdgcn_fdot2(u2h(w.z), xp[2], a, false);
      a = __builtin_amdgcn_fdot2(u2h(w.w), xp[3], a, false);
      P2[o] = a;
    }
  }

  float l1 = 0.f, l2 = 0.f;
  #pragma unroll
  for (int it = 0; it < NITER; ++it) {
    const float e1 = (it == 0) ? 1.f : __expf(l1);
    const float e2 = has2 ? ((it == 0) ? 1.f : __expf(l2)) : 0.f;

    float sp[kO + 1];
    sp[kO] = e1 + e2;
    #pragma unroll
    for (int o = 0; o < kO; ++o) sp[o] = e1 * P1[o] + e2 * P2[o];

    #pragma unroll
    for (int v = 0; v <= kO; ++v) {
      sp[v] = dpp_xor1_add(sp[v]);
      sp[v] = dpp_xor2_add(sp[v]);
    }
    if ((t & 3) == 0) {
      float* row = &red[(t >> 2) * RST];
      #pragma unroll
      for (int q = 0; q < 4; ++q)
        *reinterpret_cast<float4*>(row + 4 * q) =
            make_float4(sp[4*q], sp[4*q+1], sp[4*q+2], sp[4*q+3]);
      row[16] = sp[16];
    }
    __syncthreads();
    if (t < 136) {                       // 8 q-groups x 17 cols, stride-8 rows
      const int q = t / 17, col = t - q * 17;
      float a = 0.f;
      #pragma unroll
      for (int rr = 0; rr < 16; ++rr) a += red[(rr * 8 + q) * RST + col];
      red2[q * RST + col] = a;
    }
    __syncthreads();
    if (t < 17) {
      float a = 0.f;
      #pragma unroll
      for (int q = 0; q < 8; ++q) a += red2[q * RST + t];
      shs[t] = a;
    }
    __syncthreads();

    const float Zi = 1.f / shs[kO];
    float ss = 0.f;
    #pragma unroll
    for (int o = 0; o < kO; ++o) ss += shs[o] * shs[o];
    const float sn = ss * Zi * Zi;
    const float g  = Zi * sqrtf(sn) / (1.f + sn);

    if (it < NITER - 1) {
      float d1 = 0.f, d2 = 0.f;
      #pragma unroll
      for (int o = 0; o < kO; ++o) { d1 += P1[o] * shs[o]; d2 += P2[o] * shs[o]; }
      l1 += d1 * g;
      if (has2) l2 += d2 * g;
    } else {
      if (t < kO) out[(size_t)b * kO * kNC + t * kNC + c] = shs[t] * g;
    }
  }
}

// ---------------- fused cooperative kernel: convert W, grid-sync, route ----
__global__ __launch_bounds__(MT, 4) void caps_fused(
    const float* __restrict__ x, const float* __restrict__ W,
    unsigned short* __restrict__ Wb, float* __restrict__ out) {
  __shared__ float lds[64 * 132];       // 33792 B; phase B overlays into it
  const int t = threadIdx.x;

  // ---- Phase A: fp32 [c][r][i][o] -> fp16 [c][o][r][i], 64-row tiles ----
  for (int tile = blockIdx.x; tile < kNC * 13; tile += gridDim.x) {
    const int c  = tile / 13, tt = tile - c * 13;
    const int r0 = tt * 64;
    const int RT = (tt == 12) ? (kR - 768) : 64;   // 32 or 64 rows
    const float4* src =
        reinterpret_cast<const float4*>(W + ((size_t)c * kR + r0) * kCin * kO);
    const int n4 = RT * 32;
    for (int i4 = t; i4 < n4; i4 += MT) {
      const float4 v = src[i4];
      const int fi = i4 * 4, row = fi >> 7, pos = fi & 127;
      *reinterpret_cast<float4*>(&lds[row * 132 + pos]) = v;
    }
    __syncthreads();
    const int o = t >> 5;               // 0..15
    for (int rl = (t & 31); rl < RT; rl += 32) {
      unsigned int pk[4];
      #pragma unroll
      for (int q = 0; q < 4; ++q) {
        const unsigned int lo = f2h(lds[rl * 132 + (2 * q + 0) * 16 + o]);
        const unsigned int hi = f2h(lds[rl * 132 + (2 * q + 1) * 16 + o]);
        pk[q] = lo | (hi << 16);
      }
      reinterpret_cast<uint4*>(Wb)[(size_t)(c * kO + o) * kR + (r0 + rl)] =
          make_uint4(pk[0], pk[1], pk[2], pk[3]);
    }
    __syncthreads();
  }

  // Device-scope release of Wb, grid-wide barrier, device-scope acquire.
  __threadfence();
  cg::this_grid().sync();
  __threadfence();

  // ---- Phase B: grid-stride over the 8192 (c,b) items ----
  float* red  = lds;                    // 128 x 20
  float* red2 = lds + 128 * 20;         // 8 x 20
  float* shs  = lds + 136 * 20;         // 20
  for (int w = blockIdx.x; w < kNC * kB; w += gridDim.x) {
    const int xcd = w & 7;
    const int kk  = w >> 3;
    const int c   = ((kk >> 6) << 3) + xcd;   // XCD-local c reuse
    const int b   = kk & 63;
    route_item(x, Wb, out, c, b, t, red, red2, shs);
  }
}

// ---------------- fallback pair (R7-proven), used if coop launch fails -----
__global__ __launch_bounds__(CT) void conv_w(const float* __restrict__ W,
                                             unsigned short* __restrict__ Wb) {
  __shared__ float tile[80 * 132];
  const int blk = blockIdx.x;
  const int c  = blk / 10;
  const int rt = blk - c * 10;
  const int r0 = rt * 80;
  const int t  = threadIdx.x;

  const float4* src =
      reinterpret_cast<const float4*>(W + ((size_t)c * kR + r0) * kCin * kO);
  #pragma unroll
  for (int k2 = 0; k2 < 10; ++k2) {
    const int i4  = t + k2 * CT;
    const float4 v = src[i4];
    const int fi = i4 * 4, row = fi >> 7, pos = fi & 127;
    *reinterpret_cast<float4*>(&tile[row * 132 + pos]) = v;
  }
  __syncthreads();
  const int o = t >> 4;
  #pragma unroll
  for (int k2 = 0; k2 < 5; ++k2) {
    const int rl = (t & 15) + 16 * k2;
    unsigned int pk[4];
    #pragma unroll
    for (int q = 0; q < 4; ++q) {
      const unsigned int lo = f2h(tile[rl * 132 + (2 * q + 0) * 16 + o]);
      const unsigned int hi = f2h(tile[rl * 132 + (2 * q + 1) * 16 + o]);
      pk[q] = lo | (hi << 16);
    }
    reinterpret_cast<uint4*>(Wb)[(size_t)(c * kO + o) * kR + (r0 + rl)] =
        make_uint4(pk[0], pk[1], pk[2], pk[3]);
  }
}

__global__ __launch_bounds__(MT, 4) void caps_route(
    const float* __restrict__ x, const unsigned short* __restrict__ Wb,
    float* __restrict__ out) {
  __shared__ float red[128 * 20];
  __shared__ float red2[8 * 20];
  __shared__ float shs[20];
  const int t   = threadIdx.x;
  const int j   = blockIdx.x;
  const int xcd = j & 7;
  const int kk  = j >> 3;
  const int c   = ((kk >> 6) << 3) + xcd;
  const int b   = kk & 63;
  route_item(x, Wb, out, c, b, t, red, red2, shs);
}

// ---- fallback (no workspace): fp32 W direct ------------------------------
__global__ __launch_bounds__(MT, 4) void caps_route_f32(
    const float* __restrict__ x, const float* __restrict__ W,
    float* __restrict__ out) {
  constexpr int RST = 20;
  __shared__ float red[128 * RST];
  __shared__ float red2[8 * RST];
  __shared__ float shs[RST];

  const int t   = threadIdx.x;
  const int j   = blockIdx.x;
  const int xcd = j & 7;
  const int kk  = j >> 3;
  const int c   = ((kk >> 6) << 3) + xcd;
  const int b   = kk & 63;

  const float* xb  = x + (size_t)b * kCin * kR;
  const bool  has2 = (t < kR - MT);
  const int   r1   = t, r2 = MT + t;

  float P1[kO], P2[kO];
  #pragma unroll
  for (int o = 0; o < kO; ++o) P2[o] = 0.f;
  {
    float xa[kCin];
    #pragma unroll
    for (int i = 0; i < kCin; ++i) xa[i] = xb[i * kR + r1];
    const float* Wc = W + ((size_t)c * kR + r1) * kCin * kO;
    #pragma unroll
    for (int o = 0; o < kO; ++o) {
      float acc = 0.f;
      #pragma unroll
      for (int i = 0; i < kCin; ++i) acc += xa[i] * Wc[i * kO + o];
      P1[o] = acc;
    }
  }
  if (has2) {
    float xa[kCin];
    #pragma unroll
    for (int i = 0; i < kCin; ++i) xa[i] = xb[i * kR + r2];
    const float* Wc = W + ((size_t)c * kR + r2) * kCin * kO;
    #pragma unroll
    for (int o = 0; o < kO; ++o) {
      float acc = 0.f;
      #pragma unroll
      for (int i = 0; i < kCin; ++i) acc += xa[i] * Wc[i * kO + o];
      P2[o] = acc;
    }
  }

  float l1 = 0.f, l2 = 0.f;
  #pragma unroll
  for (int it = 0; it < NITER; ++it) {
    const float e1 = (it == 0) ? 1.f : __expf(l1);
    const float e2 = has2 ? ((it == 0) ? 1.f : __expf(l2)) : 0.f;
    float sp[kO + 1];
    sp[kO] = e1 + e2;
    #pragma unroll
    for (int o = 0; o < kO; ++o) sp[o] = e1 * P1[o] + e2 * P2[o];
    #pragma unroll
    for (int v = 0; v <= kO; ++v) {
      sp[v] = dpp_xor1_add(sp[v]);
      sp[v] = dpp_xor2_add(sp[v]);
    }
    if ((t & 3) == 0) {
      float* row = &red[(t >> 2) * RST];
      #pragma unroll
      for (int q = 0; q < 4; ++q)
        *reinterpret_cast<float4*>(row + 4 * q) =
            make_float4(sp[4*q], sp[4*q+1], sp[4*q+2], sp[4*q+3]);
      row[16] = sp[16];
    }
    __syncthreads();
    if (t < 136) {
      const int q = t / 17, col = t - q * 17;
      float a = 0.f;
      #pragma unroll
      for (int rr = 0; rr < 16; ++rr) a += red[(rr * 8 + q) * RST + col];
      red2[q * RST + col] = a;
    }
    __syncthreads();
    if (t < 17) {
      float a = 0.f;
      #pragma unroll
      for (int q = 0; q < 8; ++q) a += red2[q * RST + t];
      shs[t] = a;
    }
    __syncthreads();
    const float Zi = 1.f / shs[kO];
    float ss = 0.f;
    #pragma unroll
    for (int o = 0; o < kO; ++o) ss += shs[o] * shs[o];
    const float sn = ss * Zi * Zi;
    const float g  = Zi * sqrtf(sn) / (1.f + sn);
    if (it < NITER - 1) {
      float d1 = 0.f, d2 = 0.f;
      #pragma unroll
      for (int o = 0; o < kO; ++o) { d1 += P1[o] * shs[o]; d2 += P2[o] * shs[o]; }
      l1 += d1 * g;
      if (has2) l2 += d2 * g;
    } else {
      if (t < kO) out[(size_t)b * kO * kNC + t * kNC + c] = shs[t] * g;
    }
  }
}

}  // namespace

extern "C" void kernel_launch(void* const* d_in, const int* in_sizes, int n_in,
                              void* d_out, int out_size, void* d_ws, size_t ws_size,
                              hipStream_t stream) {
  const float* x = (const float*)d_in[0];   // [64, 8, 800] fp32
  const float* W = (const float*)d_in[1];   // [128, 800, 8, 16] fp32
  float* out = (float*)d_out;               // [64, 16, 128] fp32
  (void)in_sizes; (void)n_in; (void)out_size;

  if (ws_size >= WS_NEEDED) {
    unsigned short* Wb = (unsigned short*)d_ws;
    int occ = 0;
    hipError_t qe = hipOccupancyMaxActiveBlocksPerMultiprocessor(&occ, caps_fused, MT, 0);
    if (qe != hipSuccess || occ < 1) occ = 1;
    if (occ > 4) occ = 4;
    const float* xa = x; const float* Wa = W;
    unsigned short* wba = Wb; float* oa = out;
    void* args[] = {(void*)&xa, (void*)&Wa, (void*)&wba, (void*)&oa};
    hipError_t err = hipLaunchCooperativeKernel(
        caps_fused, dim3(256 * occ), dim3(MT), args, 0, stream);
    if (err != hipSuccess) {
      // deterministic fallback: proven two-kernel path
      conv_w<<<dim3(kNC * 10), dim3(CT), 0, stream>>>(W, Wb);
      caps_route<<<dim3(kNC * kB), dim3(MT), 0, stream>>>(x, Wb, out);
    }
  } else {
    caps_route_f32<<<dim3(kNC * kB), dim3(MT), 0, stream>>>(x, W, out);
  }
}

// Round 11
// 321.546 us; speedup vs baseline: 1.4361x; 1.4361x over previous
//
#include <hip/hip_runtime.h>
#include <math.h>

namespace {

constexpr int kB   = 64;
constexpr int kCin = 8;
constexpr int kR   = 800;
constexpr int kNC  = 128;
constexpr int kO   = 16;
constexpr int MT   = 512;   // main kernel TPB
constexpr int NITER = 3;
constexpr int N8   = kNC * kR * kCin * kO / 8;   // 1,638,400 8-elt groups
constexpr size_t WS_NEEDED =
    (size_t)kNC * kO * kR * kCin * sizeof(unsigned short);  // 26,214,400 B

typedef _Float16 half2v __attribute__((ext_vector_type(2)));

__device__ __forceinline__ half2v u2h(unsigned int u) {
  union { unsigned int u; half2v h; } x;
  x.u = u;
  return x.h;
}

__device__ __forceinline__ unsigned int pack2(float a, float b) {
  union { _Float16 h[2]; unsigned int u; } x;
  x.h[0] = (_Float16)a;
  x.h[1] = (_Float16)b;
  return x.u;
}

// DPP quad-perm adds: xor1 = perm{1,0,3,2} = 0xB1, xor2 = perm{2,3,0,1} = 0x4E.
__device__ __forceinline__ float dpp_xor1_add(float v) {
  const int o = __builtin_amdgcn_mov_dpp(__float_as_int(v), 0xB1, 0xF, 0xF, true);
  return v + __int_as_float(o);
}
__device__ __forceinline__ float dpp_xor2_add(float v) {
  const int o = __builtin_amdgcn_mov_dpp(__float_as_int(v), 0x4E, 0xF, 0xF, true);
  return v + __int_as_float(o);
}

// ---- W conversion: fp32 -> fp16, SAME layout [c][r][i][o]. Pure streaming:
// thread i handles 8 consecutive floats (2x float4 read, 1x uint4 write),
// both sides perfectly coalesced. No LDS, no barriers.
__global__ __launch_bounds__(256) void conv_w(const float4* __restrict__ src,
                                              uint4* __restrict__ dst) {
  const int i = blockIdx.x * 256 + threadIdx.x;
  if (i < N8) {
    const float4 a = src[2 * i];
    const float4 b = src[2 * i + 1];
    dst[i] = make_uint4(pack2(a.x, a.y), pack2(a.z, a.w),
                        pack2(b.x, b.y), pack2(b.z, b.w));
  }
}

// -------- main: R7-proven structure; W row-contiguous fp16 [c][r][i][o] ----
__global__ __launch_bounds__(MT, 4) void caps_route(
    const float* __restrict__ x, const unsigned short* __restrict__ Wb,
    float* __restrict__ out) {
  constexpr int RST = 20;               // 17 cols + 3 pad (16B-aligned rows)
  __shared__ float red[128 * RST];      // 10 KB
  __shared__ float red2[8 * RST];
  __shared__ float shs[RST];

  const int t = threadIdx.x;
  // XCD swizzle: consecutive resident blocks on one XCD share c
  // (W[c] fp16 = 204.8 KB; 16 c's/XCD = 3.3 MB < 4 MB L2).
  const int j   = blockIdx.x;
  const int xcd = j & 7;
  const int kk  = j >> 3;               // 0..1023
  const int c   = ((kk >> 6) << 3) + xcd;
  const int b   = kk & 63;

  const float* xb  = x + (size_t)b * kCin * kR;
  const bool  has2 = (t < kR - MT);     // t < 288 owns second row r2
  const int   r1   = t, r2 = MT + t;

  float P1[kO], P2[kO];
  #pragma unroll
  for (int o = 0; o < kO; ++o) P2[o] = 0.f;

  // -------- Phase 1: per-thread row = 256 contiguous bytes (16 uint4).
  // Packed v_pk_fma_f16: each uint = halfs (o, o+1) for one i; xh[i] = {xi,xi}.
  {
    half2v xh[kCin];
    #pragma unroll
    for (int i = 0; i < kCin; ++i) {
      const _Float16 h = (_Float16)xb[i * kR + r1];
      xh[i] = half2v{h, h};
    }
    const uint4* Wr = reinterpret_cast<const uint4*>(Wb) +
                      ((size_t)c * kR + r1) * 16;
    half2v acc[8];
    #pragma unroll
    for (int q = 0; q < 8; ++q) acc[q] = half2v{(_Float16)0.f, (_Float16)0.f};
    #pragma unroll
    for (int i = 0; i < kCin; ++i) {
      const uint4 wa = Wr[2 * i];       // o 0..7
      const uint4 wb2 = Wr[2 * i + 1];  // o 8..15
      acc[0] += u2h(wa.x) * xh[i];
      acc[1] += u2h(wa.y) * xh[i];
      acc[2] += u2h(wa.z) * xh[i];
      acc[3] += u2h(wa.w) * xh[i];
      acc[4] += u2h(wb2.x) * xh[i];
      acc[5] += u2h(wb2.y) * xh[i];
      acc[6] += u2h(wb2.z) * xh[i];
      acc[7] += u2h(wb2.w) * xh[i];
    }
    #pragma unroll
    for (int q = 0; q < 8; ++q) {
      P1[2 * q + 0] = (float)acc[q].x;
      P1[2 * q + 1] = (float)acc[q].y;
    }
  }
  if (has2) {
    half2v xh[kCin];
    #pragma unroll
    for (int i = 0; i < kCin; ++i) {
      const _Float16 h = (_Float16)xb[i * kR + r2];
      xh[i] = half2v{h, h};
    }
    const uint4* Wr = reinterpret_cast<const uint4*>(Wb) +
                      ((size_t)c * kR + r2) * 16;
    half2v acc[8];
    #pragma unroll
    for (int q = 0; q < 8; ++q) acc[q] = half2v{(_Float16)0.f, (_Float16)0.f};
    #pragma unroll
    for (int i = 0; i < kCin; ++i) {
      const uint4 wa = Wr[2 * i];
      const uint4 wb2 = Wr[2 * i + 1];
      acc[0] += u2h(wa.x) * xh[i];
      acc[1] += u2h(wa.y) * xh[i];
      acc[2] += u2h(wa.z) * xh[i];
      acc[3] += u2h(wa.w) * xh[i];
      acc[4] += u2h(wb2.x) * xh[i];
      acc[5] += u2h(wb2.y) * xh[i];
      acc[6] += u2h(wb2.z) * xh[i];
      acc[7] += u2h(wb2.w) * xh[i];
    }
    #pragma unroll
    for (int q = 0; q < 8; ++q) {
      P2[2 * q + 0] = (float)acc[q].x;
      P2[2 * q + 1] = (float)acc[q].y;
    }
  }

  // -------- Phase 2: 3 routing iterations (R7-proven + stride-8 tree) ------
  float l1 = 0.f, l2 = 0.f;
  #pragma unroll
  for (int it = 0; it < NITER; ++it) {
    const float e1 = (it == 0) ? 1.f : __expf(l1);
    const float e2 = has2 ? ((it == 0) ? 1.f : __expf(l2)) : 0.f;

    float sp[kO + 1];
    sp[kO] = e1 + e2;
    #pragma unroll
    for (int o = 0; o < kO; ++o) sp[o] = e1 * P1[o] + e2 * P2[o];

    #pragma unroll
    for (int v = 0; v <= kO; ++v) {
      sp[v] = dpp_xor1_add(sp[v]);
      sp[v] = dpp_xor2_add(sp[v]);
    }
    if ((t & 3) == 0) {
      float* row = &red[(t >> 2) * RST];
      #pragma unroll
      for (int q = 0; q < 4; ++q)
        *reinterpret_cast<float4*>(row + 4 * q) =
            make_float4(sp[4*q], sp[4*q+1], sp[4*q+2], sp[4*q+3]);
      row[16] = sp[16];
    }
    __syncthreads();
    if (t < 136) {   // 8 q-groups x 17 cols; stride-8 rows mix q into bank
      const int q = t / 17, col = t - q * 17;
      float a = 0.f;
      #pragma unroll
      for (int rr = 0; rr < 16; ++rr) a += red[(rr * 8 + q) * RST + col];
      red2[q * RST + col] = a;
    }
    __syncthreads();
    if (t < 17) {
      float a = 0.f;
      #pragma unroll
      for (int q = 0; q < 8; ++q) a += red2[q * RST + t];
      shs[t] = a;
    }
    __syncthreads();

    const float Zi = 1.f / shs[kO];
    float ss = 0.f;
    #pragma unroll
    for (int o = 0; o < kO; ++o) ss += shs[o] * shs[o];
    const float sn = ss * Zi * Zi;
    const float g  = Zi * sqrtf(sn) / (1.f + sn);

    if (it < NITER - 1) {
      float d1 = 0.f, d2 = 0.f;
      #pragma unroll
      for (int o = 0; o < kO; ++o) { d1 += P1[o] * shs[o]; d2 += P2[o] * shs[o]; }
      l1 += d1 * g;
      if (has2) l2 += d2 * g;
    } else {
      if (t < kO) out[(size_t)b * kO * kNC + t * kNC + c] = shs[t] * g;
    }
  }
}

// ---- fallback (no workspace): fp32 W direct ------------------------------
__global__ __launch_bounds__(MT, 4) void caps_route_f32(
    const float* __restrict__ x, const float* __restrict__ W,
    float* __restrict__ out) {
  constexpr int RST = 20;
  __shared__ float red[128 * RST];
  __shared__ float red2[8 * RST];
  __shared__ float shs[RST];

  const int t   = threadIdx.x;
  const int j   = blockIdx.x;
  const int xcd = j & 7;
  const int kk  = j >> 3;
  const int c   = ((kk >> 6) << 3) + xcd;
  const int b   = kk & 63;

  const float* xb  = x + (size_t)b * kCin * kR;
  const bool  has2 = (t < kR - MT);
  const int   r1   = t, r2 = MT + t;

  float P1[kO], P2[kO];
  #pragma unroll
  for (int o = 0; o < kO; ++o) P2[o] = 0.f;
  {
    float xa[kCin];
    #pragma unroll
    for (int i = 0; i < kCin; ++i) xa[i] = xb[i * kR + r1];
    const float* Wc = W + ((size_t)c * kR + r1) * kCin * kO;
    #pragma unroll
    for (int o = 0; o < kO; ++o) {
      float acc = 0.f;
      #pragma unroll
      for (int i = 0; i < kCin; ++i) acc += xa[i] * Wc[i * kO + o];
      P1[o] = acc;
    }
  }
  if (has2) {
    float xa[kCin];
    #pragma unroll
    for (int i = 0; i < kCin; ++i) xa[i] = xb[i * kR + r2];
    const float* Wc = W + ((size_t)c * kR + r2) * kCin * kO;
    #pragma unroll
    for (int o = 0; o < kO; ++o) {
      float acc = 0.f;
      #pragma unroll
      for (int i = 0; i < kCin; ++i) acc += xa[i] * Wc[i * kO + o];
      P2[o] = acc;
    }
  }

  float l1 = 0.f, l2 = 0.f;
  #pragma unroll
  for (int it = 0; it < NITER; ++it) {
    const float e1 = (it == 0) ? 1.f : __expf(l1);
    const float e2 = has2 ? ((it == 0) ? 1.f : __expf(l2)) : 0.f;
    float sp[kO + 1];
    sp[kO] = e1 + e2;
    #pragma unroll
    for (int o = 0; o < kO; ++o) sp[o] = e1 * P1[o] + e2 * P2[o];
    #pragma unroll
    for (int v = 0; v <= kO; ++v) {
      sp[v] = dpp_xor1_add(sp[v]);
      sp[v] = dpp_xor2_add(sp[v]);
    }
    if ((t & 3) == 0) {
      float* row = &red[(t >> 2) * RST];
      #pragma unroll
      for (int q = 0; q < 4; ++q)
        *reinterpret_cast<float4*>(row + 4 * q) =
            make_float4(sp[4*q], sp[4*q+1], sp[4*q+2], sp[4*q+3]);
      row[16] = sp[16];
    }
    __syncthreads();
    if (t < 136) {
      const int q = t / 17, col = t - q * 17;
      float a = 0.f;
      #pragma unroll
      for (int rr = 0; rr < 16; ++rr) a += red[(rr * 8 + q) * RST + col];
      red2[q * RST + col] = a;
    }
    __syncthreads();
    if (t < 17) {
      float a = 0.f;
      #pragma unroll
      for (int q = 0; q < 8; ++q) a += red2[q * RST + t];
      shs[t] = a;
    }
    __syncthreads();
    const float Zi = 1.f / shs[kO];
    float ss = 0.f;
    #pragma unroll
    for (int o = 0; o < kO; ++o) ss += shs[o] * shs[o];
    const float sn = ss * Zi * Zi;
    const float g  = Zi * sqrtf(sn) / (1.f + sn);
    if (it < NITER - 1) {
      float d1 = 0.f, d2 = 0.f;
      #pragma unroll
      for (int o = 0; o < kO; ++o) { d1 += P1[o] * shs[o]; d2 += P2[o] * shs[o]; }
      l1 += d1 * g;
      if (has2) l2 += d2 * g;
    } else {
      if (t < kO) out[(size_t)b * kO * kNC + t * kNC + c] = shs[t] * g;
    }
  }
}

}  // namespace

extern "C" void kernel_launch(void* const* d_in, const int* in_sizes, int n_in,
                              void* d_out, int out_size, void* d_ws, size_t ws_size,
                              hipStream_t stream) {
  const float* x = (const float*)d_in[0];   // [64, 8, 800] fp32
  const float* W = (const float*)d_in[1];   // [128, 800, 8, 16] fp32
  float* out = (float*)d_out;               // [64, 16, 128] fp32
  (void)in_sizes; (void)n_in; (void)out_size;

  if (ws_size >= WS_NEEDED) {
    unsigned short* Wb = (unsigned short*)d_ws;
    const int cgrid = (N8 + 255) / 256;   // 6400 blocks, one 8-elt group/thread
    conv_w<<<dim3(cgrid), dim3(256), 0, stream>>>(
        reinterpret_cast<const float4*>(W), reinterpret_cast<uint4*>(Wb));
    caps_route<<<dim3(kNC * kB), dim3(MT), 0, stream>>>(x, Wb, out);
  } else {
    caps_route_f32<<<dim3(kNC * kB), dim3(MT), 0, stream>>>(x, W, out);
  }
}

// Round 12
// 205.032 us; speedup vs baseline: 2.2522x; 1.5683x over previous
//
#include <hip/hip_runtime.h>
#include <math.h>

namespace {

constexpr int kB   = 64;
constexpr int kCin = 8;
constexpr int kR   = 800;
constexpr int kNC  = 128;
constexpr int kO   = 16;
constexpr int CT   = 256;   // conversion kernel TPB
constexpr int MT   = 512;   // main kernel TPB
constexpr int NITER = 3;
constexpr size_t WS_NEEDED =
    (size_t)kNC * kO * kR * kCin * sizeof(unsigned short);  // 26,214,400 B

typedef _Float16 half2v __attribute__((ext_vector_type(2)));

__device__ __forceinline__ half2v u2h(unsigned int u) {
  union { unsigned int u; half2v h; } x;
  x.u = u;
  return x.h;
}

__device__ __forceinline__ unsigned short f2h(float f) {
  union { _Float16 h; unsigned short s; } x;
  x.h = (_Float16)f;
  return x.s;
}

// DPP quad-perm adds: xor1 = perm{1,0,3,2} = 0xB1, xor2 = perm{2,3,0,1} = 0x4E.
__device__ __forceinline__ float dpp_xor1_add(float v) {
  const int o = __builtin_amdgcn_mov_dpp(__float_as_int(v), 0xB1, 0xF, 0xF, true);
  return v + __int_as_float(o);
}
__device__ __forceinline__ float dpp_xor2_add(float v) {
  const int o = __builtin_amdgcn_mov_dpp(__float_as_int(v), 0x4E, 0xF, 0xF, true);
  return v + __int_as_float(o);
}

// ---- W conversion: fp32 [c][r][i][o] -> fp16 [c][o][r][i] (uint4 = 8 i's) --
// R7-proven 80-row tile transpose.
__global__ __launch_bounds__(CT) void conv_w(const float* __restrict__ W,
                                             unsigned short* __restrict__ Wb) {
  __shared__ float tile[80 * 132];   // 80 r-rows x 128 cols (+4 pad) = 42.2 KB
  const int blk = blockIdx.x;        // c*10 + rt
  const int c  = blk / 10;
  const int rt = blk - c * 10;
  const int r0 = rt * 80;
  const int t  = threadIdx.x;

  const float4* src =
      reinterpret_cast<const float4*>(W + ((size_t)c * kR + r0) * kCin * kO);
  #pragma unroll
  for (int k2 = 0; k2 < 10; ++k2) {
    const int i4  = t + k2 * CT;
    const float4 v = src[i4];
    const int fi = i4 * 4, row = fi >> 7, pos = fi & 127;
    *reinterpret_cast<float4*>(&tile[row * 132 + pos]) = v;
  }
  __syncthreads();

  const int o = t >> 4;
  #pragma unroll
  for (int k2 = 0; k2 < 5; ++k2) {
    const int rl = (t & 15) + 16 * k2;
    unsigned int pk[4];
    #pragma unroll
    for (int q = 0; q < 4; ++q) {
      const unsigned int lo = f2h(tile[rl * 132 + (2 * q + 0) * 16 + o]);
      const unsigned int hi = f2h(tile[rl * 132 + (2 * q + 1) * 16 + o]);
      pk[q] = lo | (hi << 16);
    }
    reinterpret_cast<uint4*>(Wb)[(size_t)(c * kO + o) * kR + (r0 + rl)] =
        make_uint4(pk[0], pk[1], pk[2], pk[3]);
  }
}

// ---- main: R7 structure + packed-fp16 P (frees 16 VGPR -> 8-deep load
// chunks in phase 1) + stride-8 tree-read bank fix ----
__global__ __launch_bounds__(MT, 4) void caps_route(
    const float* __restrict__ x, const unsigned short* __restrict__ Wb,
    float* __restrict__ out) {
  constexpr int RST = 20;               // 17 cols + 3 pad (16B-aligned rows)
  __shared__ float red[128 * RST];      // 10 KB
  __shared__ float red2[8 * RST];
  __shared__ float shs[RST];

  const int t = threadIdx.x;
  // XCD swizzle: 16 c's per XCD -> fp16 W working set 3.3 MB < 4 MB L2.
  const int j   = blockIdx.x;
  const int xcd = j & 7;
  const int kk  = j >> 3;               // 0..1023
  const int c   = ((kk >> 6) << 3) + xcd;
  const int b   = kk & 63;

  const float* xb  = x + (size_t)b * kCin * kR;
  const bool  has2 = (t < kR - MT);     // t < 288 owns second row r2
  const int   r1   = t, r2 = MT + t;

  // Priors stored packed: 8 half2v per row (8 VGPR vs 16 fp32).
  half2v P1[8], P2[8];
  #pragma unroll
  for (int q = 0; q < 8; ++q) P2[q] = half2v{(_Float16)0.f, (_Float16)0.f};

  const uint4* Wc = reinterpret_cast<const uint4*>(Wb) + (size_t)c * kO * kR;

  // -------- Phase 1: fdot2 rows; explicit 8-deep load chunks ----------------
  {
    half2v xp[4];
    #pragma unroll
    for (int q = 0; q < 4; ++q)
      xp[q] = half2v{(_Float16)xb[(2*q) * kR + r1], (_Float16)xb[(2*q+1) * kR + r1]};
    float p[16];
    #pragma unroll
    for (int ob = 0; ob < 2; ++ob) {
      uint4 w[8];
      #pragma unroll
      for (int u = 0; u < 8; ++u) w[u] = Wc[(size_t)(ob * 8 + u) * kR + r1];
      #pragma unroll
      for (int u = 0; u < 8; ++u) {
        float a = __builtin_amdgcn_fdot2(u2h(w[u].x), xp[0], 0.f, false);
        a = __builtin_amdgcn_fdot2(u2h(w[u].y), xp[1], a, false);
        a = __builtin_amdgcn_fdot2(u2h(w[u].z), xp[2], a, false);
        a = __builtin_amdgcn_fdot2(u2h(w[u].w), xp[3], a, false);
        p[ob * 8 + u] = a;
      }
    }
    #pragma unroll
    for (int q = 0; q < 8; ++q)
      P1[q] = half2v{(_Float16)p[2*q], (_Float16)p[2*q+1]};
  }
  if (has2) {
    half2v xp[4];
    #pragma unroll
    for (int q = 0; q < 4; ++q)
      xp[q] = half2v{(_Float16)xb[(2*q) * kR + r2], (_Float16)xb[(2*q+1) * kR + r2]};
    float p[16];
    #pragma unroll
    for (int ob = 0; ob < 2; ++ob) {
      uint4 w[8];
      #pragma unroll
      for (int u = 0; u < 8; ++u) w[u] = Wc[(size_t)(ob * 8 + u) * kR + r2];
      #pragma unroll
      for (int u = 0; u < 8; ++u) {
        float a = __builtin_amdgcn_fdot2(u2h(w[u].x), xp[0], 0.f, false);
        a = __builtin_amdgcn_fdot2(u2h(w[u].y), xp[1], a, false);
        a = __builtin_amdgcn_fdot2(u2h(w[u].z), xp[2], a, false);
        a = __builtin_amdgcn_fdot2(u2h(w[u].w), xp[3], a, false);
        p[ob * 8 + u] = a;
      }
    }
    #pragma unroll
    for (int q = 0; q < 8; ++q)
      P2[q] = half2v{(_Float16)p[2*q], (_Float16)p[2*q+1]};
  }

  // -------- Phase 2: 3 routing iterations (fp32 math; unpack P per iter) ----
  float l1 = 0.f, l2 = 0.f;
  #pragma unroll
  for (int it = 0; it < NITER; ++it) {
    const float e1 = (it == 0) ? 1.f : __expf(l1);
    const float e2 = has2 ? ((it == 0) ? 1.f : __expf(l2)) : 0.f;

    float u1[kO], u2[kO];
    #pragma unroll
    for (int q = 0; q < 8; ++q) {
      u1[2*q]   = (float)P1[q].x; u1[2*q+1] = (float)P1[q].y;
      u2[2*q]   = (float)P2[q].x; u2[2*q+1] = (float)P2[q].y;
    }

    float sp[kO + 1];
    sp[kO] = e1 + e2;
    #pragma unroll
    for (int o = 0; o < kO; ++o) sp[o] = e1 * u1[o] + e2 * u2[o];

    #pragma unroll
    for (int v = 0; v <= kO; ++v) {
      sp[v] = dpp_xor1_add(sp[v]);
      sp[v] = dpp_xor2_add(sp[v]);
    }
    if ((t & 3) == 0) {
      float* row = &red[(t >> 2) * RST];
      #pragma unroll
      for (int q = 0; q < 4; ++q)
        *reinterpret_cast<float4*>(row + 4 * q) =
            make_float4(sp[4*q], sp[4*q+1], sp[4*q+2], sp[4*q+3]);
      row[16] = sp[16];
    }
    __syncthreads();
    if (t < 136) {   // 8 q-groups x 17 cols; stride-8 rows mix q into bank
      const int q = t / 17, col = t - q * 17;
      float a = 0.f;
      #pragma unroll
      for (int rr = 0; rr < 16; ++rr) a += red[(rr * 8 + q) * RST + col];
      red2[q * RST + col] = a;
    }
    __syncthreads();
    if (t < 17) {
      float a = 0.f;
      #pragma unroll
      for (int q = 0; q < 8; ++q) a += red2[q * RST + t];
      shs[t] = a;
    }
    __syncthreads();

    const float Zi = 1.f / shs[kO];
    float ss = 0.f;
    #pragma unroll
    for (int o = 0; o < kO; ++o) ss += shs[o] * shs[o];
    const float sn = ss * Zi * Zi;
    const float g  = Zi * sqrtf(sn) / (1.f + sn);

    if (it < NITER - 1) {
      float d1 = 0.f, d2 = 0.f;
      #pragma unroll
      for (int o = 0; o < kO; ++o) { d1 += u1[o] * shs[o]; d2 += u2[o] * shs[o]; }
      l1 += d1 * g;
      if (has2) l2 += d2 * g;
    } else {
      if (t < kO) out[(size_t)b * kO * kNC + t * kNC + c] = shs[t] * g;
    }
  }
}

// ---- fallback (no workspace): fp32 W direct ------------------------------
__global__ __launch_bounds__(MT, 4) void caps_route_f32(
    const float* __restrict__ x, const float* __restrict__ W,
    float* __restrict__ out) {
  constexpr int RST = 20;
  __shared__ float red[128 * RST];
  __shared__ float red2[8 * RST];
  __shared__ float shs[RST];

  const int t   = threadIdx.x;
  const int j   = blockIdx.x;
  const int xcd = j & 7;
  const int kk  = j >> 3;
  const int c   = ((kk >> 6) << 3) + xcd;
  const int b   = kk & 63;

  const float* xb  = x + (size_t)b * kCin * kR;
  const bool  has2 = (t < kR - MT);
  const int   r1   = t, r2 = MT + t;

  float P1[kO], P2[kO];
  #pragma unroll
  for (int o = 0; o < kO; ++o) P2[o] = 0.f;
  {
    float xa[kCin];
    #pragma unroll
    for (int i = 0; i < kCin; ++i) xa[i] = xb[i * kR + r1];
    const float* Wc = W + ((size_t)c * kR + r1) * kCin * kO;
    #pragma unroll
    for (int o = 0; o < kO; ++o) {
      float acc = 0.f;
      #pragma unroll
      for (int i = 0; i < kCin; ++i) acc += xa[i] * Wc[i * kO + o];
      P1[o] = acc;
    }
  }
  if (has2) {
    float xa[kCin];
    #pragma unroll
    for (int i = 0; i < kCin; ++i) xa[i] = xb[i * kR + r2];
    const float* Wc = W + ((size_t)c * kR + r2) * kCin * kO;
    #pragma unroll
    for (int o = 0; o < kO; ++o) {
      float acc = 0.f;
      #pragma unroll
      for (int i = 0; i < kCin; ++i) acc += xa[i] * Wc[i * kO + o];
      P2[o] = acc;
    }
  }

  float l1 = 0.f, l2 = 0.f;
  #pragma unroll
  for (int it = 0; it < NITER; ++it) {
    const float e1 = (it == 0) ? 1.f : __expf(l1);
    const float e2 = has2 ? ((it == 0) ? 1.f : __expf(l2)) : 0.f;
    float sp[kO + 1];
    sp[kO] = e1 + e2;
    #pragma unroll
    for (int o = 0; o < kO; ++o) sp[o] = e1 * P1[o] + e2 * P2[o];
    #pragma unroll
    for (int v = 0; v <= kO; ++v) {
      sp[v] = dpp_xor1_add(sp[v]);
      sp[v] = dpp_xor2_add(sp[v]);
    }
    if ((t & 3) == 0) {
      float* row = &red[(t >> 2) * RST];
      #pragma unroll
      for (int q = 0; q < 4; ++q)
        *reinterpret_cast<float4*>(row + 4 * q) =
            make_float4(sp[4*q], sp[4*q+1], sp[4*q+2], sp[4*q+3]);
      row[16] = sp[16];
    }
    __syncthreads();
    if (t < 136) {
      const int q = t / 17, col = t - q * 17;
      float a = 0.f;
      #pragma unroll
      for (int rr = 0; rr < 16; ++rr) a += red[(rr * 8 + q) * RST + col];
      red2[q * RST + col] = a;
    }
    __syncthreads();
    if (t < 17) {
      float a = 0.f;
      #pragma unroll
      for (int q = 0; q < 8; ++q) a += red2[q * RST + t];
      shs[t] = a;
    }
    __syncthreads();
    const float Zi = 1.f / shs[kO];
    float ss = 0.f;
    #pragma unroll
    for (int o = 0; o < kO; ++o) ss += shs[o] * shs[o];
    const float sn = ss * Zi * Zi;
    const float g  = Zi * sqrtf(sn) / (1.f + sn);
    if (it < NITER - 1) {
      float d1 = 0.f, d2 = 0.f;
      #pragma unroll
      for (int o = 0; o < kO; ++o) { d1 += P1[o] * shs[o]; d2 += P2[o] * shs[o]; }
      l1 += d1 * g;
      if (has2) l2 += d2 * g;
    } else {
      if (t < kO) out[(size_t)b * kO * kNC + t * kNC + c] = shs[t] * g;
    }
  }
}

}  // namespace

extern "C" void kernel_launch(void* const* d_in, const int* in_sizes, int n_in,
                              void* d_out, int out_size, void* d_ws, size_t ws_size,
                              hipStream_t stream) {
  const float* x = (const float*)d_in[0];   // [64, 8, 800] fp32
  const float* W = (const float*)d_in[1];   // [128, 800, 8, 16] fp32
  float* out = (float*)d_out;               // [64, 16, 128] fp32
  (void)in_sizes; (void)n_in; (void)out_size;

  if (ws_size >= WS_NEEDED) {
    unsigned short* Wb = (unsigned short*)d_ws;
    conv_w<<<dim3(kNC * 10), dim3(CT), 0, stream>>>(W, Wb);
    caps_route<<<dim3(kNC * kB), dim3(MT), 0, stream>>>(x, Wb, out);
  } else {
    caps_route_f32<<<dim3(kNC * kB), dim3(MT), 0, stream>>>(x, W, out);
  }
}